// Round 1
// baseline (345.997 us; speedup 1.0000x reference)
//
#include <hip/hip_runtime.h>
#include <hip/hip_bf16.h>

#define NT 8192
#define DIM 512
#define NE 16

#define BM 128
#define BN 128
#define BK 32

typedef __attribute__((ext_vector_type(4))) float f32x4;
typedef __attribute__((ext_vector_type(8))) short short8;

typedef __attribute__((address_space(3))) void lds_void_t;
typedef const __attribute__((address_space(1))) void g_void_t;

__device__ inline unsigned short f2b(float f) {
  union { __hip_bfloat16 b; unsigned short u; } cv;
  cv.b = __float2bfloat16(f);  // round-to-nearest-even
  return cv.u;
}

// Convert x [NT*DIM] and W [NE*DIM*DIM] fp32 -> bf16 into workspace.
__global__ __launch_bounds__(256) void cvt_kernel(const float* __restrict__ x,
                                                  const float* __restrict__ W,
                                                  unsigned short* __restrict__ xb,
                                                  unsigned short* __restrict__ wb) {
  long t = (long)blockIdx.x * 256 + threadIdx.x;
  long i = t * 8;
  const float* src;
  unsigned short* dst;
  if (i < (long)NT * DIM) {
    src = x + i;
    dst = xb + i;
  } else {
    long j = i - (long)NT * DIM;
    src = W + j;
    dst = wb + j;
  }
  float4 v0 = reinterpret_cast<const float4*>(src)[0];
  float4 v1 = reinterpret_cast<const float4*>(src)[1];
  short8 o;
  o[0] = (short)f2b(v0.x); o[1] = (short)f2b(v0.y);
  o[2] = (short)f2b(v0.z); o[3] = (short)f2b(v0.w);
  o[4] = (short)f2b(v1.x); o[5] = (short)f2b(v1.y);
  o[6] = (short)f2b(v1.z); o[7] = (short)f2b(v1.w);
  *reinterpret_cast<short8*>(dst) = o;
}

// C[e] = x @ W[e]^T + b[e].  m97-structure: 128x128 tile, BK=32, 4 waves,
// global_load_lds(16B) staging, mfma_f32_16x16x32_bf16, fp32 out.
__global__ __launch_bounds__(256) void expert_gemm(const unsigned short* __restrict__ xb,
                                                   const unsigned short* __restrict__ wb,
                                                   const float* __restrict__ bias,
                                                   float* __restrict__ out) {
  __shared__ unsigned short Alds[BM * BK];  // 8 KB
  __shared__ unsigned short Blds[BN * BK];  // 8 KB

  const int tid = threadIdx.x;
  const int lane = tid & 63;
  const int wid = tid >> 6;

  const int bid = blockIdx.x;
  // 4096 blocks: e (16) * tn (4) * tm (64), tm fastest -> consecutive blocks
  // share the same W panel (L2 reuse).
  const int e = bid >> 8;
  const int r = bid & 255;
  const int tn = r >> 6;
  const int tm = r & 63;

  const int m0 = tm * BM;
  const int n0 = tn * BN;

  const unsigned short* Wa = wb + (size_t)e * DIM * DIM;

  // Staging: wave wid covers tile rows [wid*32, wid*32+32).
  // Each lane loads 16B = 8 bf16; LDS dest = wave base + lane*16 (HW rule).
  const int srow = lane >> 2;          // 0..15
  const int scol = (lane & 3) * 8;     // 0,8,16,24
  const unsigned short* gA = xb + (size_t)(m0 + wid * 32 + srow) * DIM + scol;
  const unsigned short* gB = Wa + (size_t)(n0 + wid * 32 + srow) * DIM + scol;
  unsigned short* lA = &Alds[wid * 1024];   // 32 rows * 32 cols
  unsigned short* lB = &Blds[wid * 1024];

  // Each wave computes a 64x64 sub-tile: wm,wn in {0,1}.
  const int wm = wid >> 1;
  const int wn = wid & 1;
  const int fr = lane & 15;            // fragment row (A) / row of B^T (col of C)
  const int fk = (lane >> 4) * 8;      // k offset within BK

  f32x4 acc[4][4] = {};

  for (int k0 = 0; k0 < DIM; k0 += BK) {
    __syncthreads();
    __builtin_amdgcn_global_load_lds((g_void_t*)(gA + k0),            (lds_void_t*)lA,         16, 0, 0);
    __builtin_amdgcn_global_load_lds((g_void_t*)(gA + 16 * DIM + k0), (lds_void_t*)(lA + 512), 16, 0, 0);
    __builtin_amdgcn_global_load_lds((g_void_t*)(gB + k0),            (lds_void_t*)lB,         16, 0, 0);
    __builtin_amdgcn_global_load_lds((g_void_t*)(gB + 16 * DIM + k0), (lds_void_t*)(lB + 512), 16, 0, 0);
    __syncthreads();  // compiler emits s_waitcnt vmcnt(0) before s_barrier

    short8 a[4], b[4];
#pragma unroll
    for (int mi = 0; mi < 4; ++mi)
      a[mi] = *reinterpret_cast<const short8*>(&Alds[(wm * 64 + mi * 16 + fr) * BK + fk]);
#pragma unroll
    for (int ni = 0; ni < 4; ++ni)
      b[ni] = *reinterpret_cast<const short8*>(&Blds[(wn * 64 + ni * 16 + fr) * BK + fk]);
#pragma unroll
    for (int mi = 0; mi < 4; ++mi)
#pragma unroll
      for (int ni = 0; ni < 4; ++ni)
        acc[mi][ni] = __builtin_amdgcn_mfma_f32_16x16x32_bf16(a[mi], b[ni], acc[mi][ni], 0, 0, 0);
  }

  // Epilogue: C row = (lane>>4)*4 + reg, col = lane&15 (verified gfx950 mapping).
  const int orow = (lane >> 4) * 4;
  float bv[4];
#pragma unroll
  for (int ni = 0; ni < 4; ++ni)
    bv[ni] = bias[e * DIM + n0 + wn * 64 + ni * 16 + fr];

  float* outE = out + (size_t)e * NT * DIM;
#pragma unroll
  for (int mi = 0; mi < 4; ++mi) {
#pragma unroll
    for (int reg = 0; reg < 4; ++reg) {
      const int row = m0 + wm * 64 + mi * 16 + orow + reg;
      float* op = outE + (size_t)row * DIM + n0 + wn * 64 + fr;
#pragma unroll
      for (int ni = 0; ni < 4; ++ni)
        op[ni * 16] = acc[mi][ni][reg] + bv[ni];
    }
  }
}

extern "C" void kernel_launch(void* const* d_in, const int* in_sizes, int n_in,
                              void* d_out, int out_size, void* d_ws, size_t ws_size,
                              hipStream_t stream) {
  const float* x = (const float*)d_in[0];
  const float* W = (const float*)d_in[1];
  const float* b = (const float*)d_in[2];
  float* out = (float*)d_out;

  unsigned short* xb = (unsigned short*)d_ws;                 // 8 MB
  unsigned short* wb = xb + (size_t)NT * DIM;                 // 8 MB

  // (NT*DIM + NE*DIM*DIM) / 8 elems-per-thread / 256 threads = 4096 blocks
  cvt_kernel<<<4096, 256, 0, stream>>>(x, W, xb, wb);

  // 16 experts * 64 m-tiles * 4 n-tiles = 4096 blocks
  expert_gemm<<<4096, 256, 0, stream>>>(xb, wb, b, out);
}